// Round 3
// baseline (371.704 us; speedup 1.0000x reference)
//
#include <hip/hip_runtime.h>
#include <math.h>

#define HH 256
#define WW 256
#define CC 64
#define NB 8
#define ROWS 8
#define TW 64

typedef float floatx4 __attribute__((ext_vector_type(4)));
typedef _Float16 half8 __attribute__((ext_vector_type(8)));

// ---------------------------------------------------------------------------
// Kernel 1: Mh[k][c] = f16( softmax(G) @ P @ softmax(A) )[k][c], row-major.
// (unchanged from verified baseline)
// ---------------------------------------------------------------------------
__global__ __launch_bounds__(1024) void prep_M(const float* __restrict__ A,
                                               const float* __restrict__ G,
                                               const float* __restrict__ P,
                                               _Float16* __restrict__ Mh) {
    __shared__ __align__(16) float As[64][68];
    __shared__ __align__(16) float Gs[64][68];
    __shared__ __align__(16) float T[64][68];

    const int t = threadIdx.x;
    const int wave = t >> 6;
    const int lane = t & 63;

    for (int r8 = 0; r8 < 8; ++r8) {
        int row = wave * 8 + r8;       // 0..127
        int r = row & 63;
        const float* src = (row < 64) ? A : G;
        float v = src[r * 64 + lane];
        float m = v;
        #pragma unroll
        for (int off = 32; off > 0; off >>= 1)
            m = fmaxf(m, __shfl_xor(m, off, 64));
        float e = __expf(v - m);
        float s = e;
        #pragma unroll
        for (int off = 32; off > 0; off >>= 1)
            s += __shfl_xor(s, off, 64);
        float o = e / s;
        if (row < 64) As[r][lane] = o; else Gs[r][lane] = o;
    }
    __syncthreads();

    // T = P @ As
    {
        const int d = t >> 4, q = t & 15;
        float4 acc = make_float4(0.f, 0.f, 0.f, 0.f);
        for (int e = 0; e < 64; ++e) {
            float p = P[d * 64 + e];
            float4 a = *(const float4*)&As[e][4 * q];
            acc.x = fmaf(p, a.x, acc.x);
            acc.y = fmaf(p, a.y, acc.y);
            acc.z = fmaf(p, a.z, acc.z);
            acc.w = fmaf(p, a.w, acc.w);
        }
        *(float4*)&T[d][4 * q] = acc;
    }
    __syncthreads();

    // M = Gs @ T ; store f16 row-major: Mh[k*64 + c]
    {
        const int k = t >> 4, q = t & 15;
        float4 acc = make_float4(0.f, 0.f, 0.f, 0.f);
        for (int d = 0; d < 64; ++d) {
            float g = Gs[k][d];
            float4 tv = *(const float4*)&T[d][4 * q];
            acc.x = fmaf(g, tv.x, acc.x);
            acc.y = fmaf(g, tv.y, acc.y);
            acc.z = fmaf(g, tv.z, acc.z);
            acc.w = fmaf(g, tv.w, acc.w);
        }
        _Float16* mp = Mh + k * 64 + 4 * q;
        mp[0] = (_Float16)acc.x;
        mp[1] = (_Float16)acc.y;
        mp[2] = (_Float16)acc.z;
        mp[3] = (_Float16)acc.w;
    }
}

// ---------------------------------------------------------------------------
// Kernel 2: fused depthwise conv (fp32 VALU) + channel mix via
// mfma_f32_16x16x32_f16 (A = M fragments in regs, B = dwT tile).
// v4: fully-coalesced global loads (conv lane = w: one instr = 64 consecutive
// floats), f16 XOR-swizzled dwT (16 KB LDS, conflict-free b128 reads, direct
// half8 B-frags), XCD-grouped flat grid (id&7 = image -> halo lines shared in
// one XCD's L2). Horizontal conv via column-sum shuffles; tile-edge halo via
// one 16-lane predicated load per row + readlane broadcasts. Stores keep the
// round-0 proven clean scalar-nt pattern. One barrier per row; dwT dbuf.
// ---------------------------------------------------------------------------
__global__ __launch_bounds__(512, 6) void fused_conv_mix(const float* __restrict__ x,
                                                         const float* __restrict__ dwgt,
                                                         const _Float16* __restrict__ Mh,
                                                         float* __restrict__ out) {
    __shared__ _Float16 dwT[2][64][64];   // [buf][w][c ^ ((w&7)<<3)], 16 KB

    const int id = blockIdx.x;
    const int b = id & 7;                 // XCD grouping: one image per XCD
    const int rr = id >> 3;
    const int tw0 = (rr & 3) * TW;
    const int h0 = (rr >> 2) * ROWS;

    const int t = threadIdx.x;
    const int wave = t >> 6;
    const int lane = t & 63;

    // ---- conv persona: lane = w offset, wave owns channels wave*8 .. +7 ----
    const int c0ch = wave * 8;
    const float* xb = x + (size_t)b * CC * HH * WW;

    // ---- mix persona ----
    const int q = lane >> 4;
    const int mrow = lane & 15;
    const int ktile = (wave & 3) * 16;
    const int phalf = (wave >> 2) * 32;

    // A-fragments: M[k = ktile + mrow][c = half*32 + q*8 + j]. Held all kernel.
    half8 af0, af1;
    {
        const half8* ap = (const half8*)(Mh + (ktile + mrow) * 64);
        af0 = ap[q];          // c0 = q*8
        af1 = ap[4 + q];      // c0 = 32 + q*8
    }

    float rows_[3][8];   // [slot][ch]: x[c][y][tw0+lane]
    float hrow[3];       // lanes 0..15 hold halo: lane l: ch=c0ch+(l>>1), side=l&1

    auto stage = [&](int s, int y) {
        if ((unsigned)y < (unsigned)HH) {
            #pragma unroll
            for (int cl = 0; cl < 8; ++cl)
                rows_[s][cl] = xb[((size_t)(c0ch + cl) * HH + y) * WW + tw0 + lane];
            float hv = 0.f;
            if (lane < 16) {
                int cc = c0ch + (lane >> 1);
                int wq = tw0 - 1 + 65 * (lane & 1);
                if ((unsigned)wq < (unsigned)WW)
                    hv = xb[((size_t)cc * HH + y) * WW + wq];
            }
            hrow[s] = hv;
        } else {
            #pragma unroll
            for (int cl = 0; cl < 8; ++cl) rows_[s][cl] = 0.f;
            hrow[s] = 0.f;
        }
    };

    stage(0, h0 - 1);
    stage(1, h0);
    stage(2, h0 + 1);

    const size_t kstride = (size_t)HH * WW;
    // store base: k = ktile + q*4 (+r), w = tw0 + phalf + mrow (+pt*16)
    float* obase = out + (((size_t)(b * CC + ktile + q * 4)) * HH + h0) * WW + tw0 + phalf + mrow;

    #pragma unroll
    for (int i = 0; i < ROWS; ++i) {
        const int sm = (i + 0) % 3;
        const int s0 = (i + 1) % 3;
        const int sp = (i + 2) % 3;

        // ---- conv row h0+i -> dwT[i&1][w][c^sw] ----
        #pragma unroll
        for (int cl = 0; cl < 8; ++cl) {
            const int cc = c0ch + cl;
            const float* wp = dwgt + cc * 9;       // uniform -> scalar loads
            const float rm = rows_[sm][cl], r0 = rows_[s0][cl], rp = rows_[sp][cl];
            // column sums at own w for kernel columns dx = 0,1,2
            float cs0 = fmaf(wp[0], rm, fmaf(wp[3], r0, wp[6] * rp));
            float cs1 = fmaf(wp[1], rm, fmaf(wp[4], r0, wp[7] * rp));
            float cs2 = fmaf(wp[2], rm, fmaf(wp[5], r0, wp[8] * rp));
            float lft = __shfl(cs0, lane - 1);     // lane 0: garbage, fixed below
            float rgt = __shfl(cs2, lane + 1);     // lane 63: garbage, fixed below
            // halo column sums from broadcast halo x values
            float bmL = __shfl(hrow[sm], 2 * cl),     b0L = __shfl(hrow[s0], 2 * cl),     bpL = __shfl(hrow[sp], 2 * cl);
            float bmR = __shfl(hrow[sm], 2 * cl + 1), b0R = __shfl(hrow[s0], 2 * cl + 1), bpR = __shfl(hrow[sp], 2 * cl + 1);
            float hl = fmaf(wp[0], bmL, fmaf(wp[3], b0L, wp[6] * bpL));
            float hr = fmaf(wp[2], bmR, fmaf(wp[5], b0R, wp[8] * bpR));
            lft = (lane == 0) ? hl : lft;
            rgt = (lane == 63) ? hr : rgt;
            float o = lft + cs1 + rgt;
            dwT[i & 1][lane][cc ^ ((lane & 7) << 3)] = (_Float16)o;
        }
        __syncthreads();

        // stage row h0+i+2 into the retiring slot (hidden under MFMA/stores)
        if (i < ROWS - 1) stage(i % 3, h0 + i + 2);

        // ---- mix via MFMA: out[k][w] = sum_c M[k][c] * dw[c][w] ----
        {
            floatx4 dd0 = (floatx4){0.f, 0.f, 0.f, 0.f};
            floatx4 dd1 = (floatx4){0.f, 0.f, 0.f, 0.f};

            {
                const int wl = phalf + mrow;
                const _Float16* bp = &dwT[i & 1][wl][0];
                const int s8 = (wl & 7) << 3;
                half8 hb0 = *(const half8*)(bp + ((q * 8) ^ s8));
                half8 hb1 = *(const half8*)(bp + ((32 + q * 8) ^ s8));
                dd0 = __builtin_amdgcn_mfma_f32_16x16x32_f16(af0, hb0, dd0, 0, 0, 0);
                dd0 = __builtin_amdgcn_mfma_f32_16x16x32_f16(af1, hb1, dd0, 0, 0, 0);
            }
            {
                const int wl = phalf + 16 + mrow;
                const _Float16* bp = &dwT[i & 1][wl][0];
                const int s8 = (wl & 7) << 3;
                half8 hb0 = *(const half8*)(bp + ((q * 8) ^ s8));
                half8 hb1 = *(const half8*)(bp + ((32 + q * 8) ^ s8));
                dd1 = __builtin_amdgcn_mfma_f32_16x16x32_f16(af0, hb0, dd1, 0, 0, 0);
                dd1 = __builtin_amdgcn_mfma_f32_16x16x32_f16(af1, hb1, dd1, 0, 0, 0);
            }

            // D layout: col(w) = mrow, row(k) = q*4 + reg
            float* orow = obase + (size_t)i * WW;
            #pragma unroll
            for (int r = 0; r < 4; ++r) {
                float* op = orow + (size_t)r * kstride;
                __builtin_nontemporal_store(dd0[r], op);        // w = tw0+phalf+mrow
                __builtin_nontemporal_store(dd1[r], op + 16);   // +16
            }
        }
    }
}

extern "C" void kernel_launch(void* const* d_in, const int* in_sizes, int n_in,
                              void* d_out, int out_size, void* d_ws, size_t ws_size,
                              hipStream_t stream) {
    const float* x    = (const float*)d_in[0];  // [8,64,256,256]
    const float* dwgt = (const float*)d_in[1];  // [64,1,3,3]
    const float* pwgt = (const float*)d_in[2];  // [64,64,1,1]
    const float* attw = (const float*)d_in[3];  // [64,64]
    const float* gatt = (const float*)d_in[4];  // [64,64]
    _Float16* Mh = (_Float16*)d_ws;             // 4096 f16 = 8 KB
    float* o  = (float*)d_out;

    prep_M<<<1, 1024, 0, stream>>>(attw, gatt, pwgt, Mh);

    fused_conv_mix<<<dim3(NB * (WW / TW) * (HH / ROWS)), 512, 0, stream>>>(x, dwgt, Mh, o);
}

// Round 4
// 265.223 us; speedup vs baseline: 1.4015x; 1.4015x over previous
//
#include <hip/hip_runtime.h>
#include <math.h>

#define HH 256
#define WW 256
#define CC 64
#define NB 8
#define ROWS 8

typedef float fvec4 __attribute__((ext_vector_type(4)));
typedef float floatx4 __attribute__((ext_vector_type(4)));
typedef _Float16 half8 __attribute__((ext_vector_type(8)));

// ---------------------------------------------------------------------------
// Kernel 1: Mh[k][c] = f16( softmax(G) @ P @ softmax(A) )[k][c], row-major.
// ---------------------------------------------------------------------------
__global__ __launch_bounds__(1024) void prep_M(const float* __restrict__ A,
                                               const float* __restrict__ G,
                                               const float* __restrict__ P,
                                               _Float16* __restrict__ Mh) {
    __shared__ __align__(16) float As[64][68];
    __shared__ __align__(16) float Gs[64][68];
    __shared__ __align__(16) float T[64][68];

    const int t = threadIdx.x;
    const int wave = t >> 6;
    const int lane = t & 63;

    for (int r8 = 0; r8 < 8; ++r8) {
        int row = wave * 8 + r8;       // 0..127
        int r = row & 63;
        const float* src = (row < 64) ? A : G;
        float v = src[r * 64 + lane];
        float m = v;
        #pragma unroll
        for (int off = 32; off > 0; off >>= 1)
            m = fmaxf(m, __shfl_xor(m, off, 64));
        float e = __expf(v - m);
        float s = e;
        #pragma unroll
        for (int off = 32; off > 0; off >>= 1)
            s += __shfl_xor(s, off, 64);
        float o = e / s;
        if (row < 64) As[r][lane] = o; else Gs[r][lane] = o;
    }
    __syncthreads();

    // T = P @ As
    {
        const int d = t >> 4, q = t & 15;
        float4 acc = make_float4(0.f, 0.f, 0.f, 0.f);
        for (int e = 0; e < 64; ++e) {
            float p = P[d * 64 + e];
            float4 a = *(const float4*)&As[e][4 * q];
            acc.x = fmaf(p, a.x, acc.x);
            acc.y = fmaf(p, a.y, acc.y);
            acc.z = fmaf(p, a.z, acc.z);
            acc.w = fmaf(p, a.w, acc.w);
        }
        *(float4*)&T[d][4 * q] = acc;
    }
    __syncthreads();

    // M = Gs @ T ; store f16 row-major: Mh[k*64 + c]
    {
        const int k = t >> 4, q = t & 15;
        float4 acc = make_float4(0.f, 0.f, 0.f, 0.f);
        for (int d = 0; d < 64; ++d) {
            float g = Gs[k][d];
            float4 tv = *(const float4*)&T[d][4 * q];
            acc.x = fmaf(g, tv.x, acc.x);
            acc.y = fmaf(g, tv.y, acc.y);
            acc.z = fmaf(g, tv.z, acc.z);
            acc.w = fmaf(g, tv.w, acc.w);
        }
        _Float16* mp = Mh + k * 64 + 4 * q;
        mp[0] = (_Float16)acc.x;
        mp[1] = (_Float16)acc.y;
        mp[2] = (_Float16)acc.z;
        mp[3] = (_Float16)acc.w;
    }
}

// ---------------------------------------------------------------------------
// Kernel 2 (v5): the round-0 kernel (verified best traffic: 286 MB, 91 us)
// with the barrier drain removed. __syncthreads -> lgkmcnt(0)+raw s_barrier:
// the rolling prefetch loads and nontemporal stores stay in flight across
// barriers (the compiler emits counted vmcnt waits at first register use),
// eliminating the per-row ~900-cycle vmcnt(0) drain that was ~50% of runtime.
// Also: XOR-swizzle dwT's c index by (w>>4)<<3 -> LDS writes 4-way -> 2-way.
// ---------------------------------------------------------------------------
__global__ __launch_bounds__(256, 4) void fused_conv_mix(const float* __restrict__ x,
                                                         const float* __restrict__ dwgt,
                                                         const _Float16* __restrict__ Mh,
                                                         float* __restrict__ out) {
    __shared__ __align__(16) float dwT[2][64][68];   // [buf][w_local][c ^ ((w>>4)<<3)]

    const int t = threadIdx.x;
    const int tw0 = blockIdx.x * 64;
    const int h0 = blockIdx.y * ROWS;
    const int b = blockIdx.z;

    // ---- conv persona ----
    const int c = t >> 2;
    const int chunk = t & 3;
    const int gw0 = tw0 + chunk * 16;
    const float* xc = x + ((size_t)(b * CC + c) * HH) * WW;

    float wg[9];
    #pragma unroll
    for (int i = 0; i < 9; ++i) wg[i] = dwgt[c * 9 + i];

    // ---- mix persona ----
    const int wave = t >> 6;          // k-block = wave*16
    const int lane = t & 63;
    const int q = lane >> 4;          // quad
    const int mrow = lane & 15;       // A row (k within tile) / B col (w within subtile)

    // A-fragments: M[k = wave*16 + mrow][c = s*32 + q*8 + j], j=0..7. Held all kernel.
    half8 af0, af1;
    {
        const half8* ap = (const half8*)(Mh + (wave * 16 + mrow) * 64);
        af0 = ap[q];          // c0 = q*8
        af1 = ap[4 + q];      // c0 = 32 + q*8
    }

    float rows[3][18];

    auto load_row = [&](float* r, int y) {
        if ((unsigned)y < (unsigned)HH) {
            const float* p = xc + y * WW + gw0;
            const float4* p4 = (const float4*)p;
            float4 v0 = p4[0], v1 = p4[1], v2 = p4[2], v3 = p4[3];
            r[1] = v0.x;  r[2] = v0.y;  r[3] = v0.z;  r[4] = v0.w;
            r[5] = v1.x;  r[6] = v1.y;  r[7] = v1.z;  r[8] = v1.w;
            r[9] = v2.x;  r[10] = v2.y; r[11] = v2.z; r[12] = v2.w;
            r[13] = v3.x; r[14] = v3.y; r[15] = v3.z; r[16] = v3.w;
            r[0]  = (gw0 > 0)       ? p[-1] : 0.f;
            r[17] = (gw0 + 16 < WW) ? p[16] : 0.f;
        } else {
            #pragma unroll
            for (int i = 0; i < 18; ++i) r[i] = 0.f;
        }
    };

    load_row(rows[0], h0 - 1);
    load_row(rows[1], h0);
    load_row(rows[2], h0 + 1);

    const size_t kstride = (size_t)HH * WW;
    const int cswz = c ^ (chunk << 3);   // write-side column swizzle (w>>4 == chunk)

    #pragma unroll
    for (int i = 0; i < ROWS; ++i) {
        const float* rm_ = rows[(i + 0) % 3];
        const float* r0_ = rows[(i + 1) % 3];
        const float* rp_ = rows[(i + 2) % 3];

        // ---- conv row h0+i -> dwT[i&1][w][c^swz] (transposed) ----
        #pragma unroll
        for (int j = 0; j < 16; ++j) {
            float a = 0.f;
            #pragma unroll
            for (int dx = 0; dx < 3; ++dx) {
                a = fmaf(wg[0 * 3 + dx], rm_[j + dx], a);
                a = fmaf(wg[1 * 3 + dx], r0_[j + dx], a);
                a = fmaf(wg[2 * 3 + dx], rp_[j + dx], a);
            }
            dwT[i & 1][chunk * 16 + j][cswz] = a;   // 2-way banked: free
        }

        // LDS drain only; global loads/stores stay in flight across the barrier.
        asm volatile("s_waitcnt lgkmcnt(0)" ::: "memory");
        __builtin_amdgcn_s_barrier();

        // prefetch row h0+i+2 into the retiring buffer (register-renamed)
        if (i < ROWS - 1) load_row(rows[i % 3], h0 + i + 2);

        // ---- mix via MFMA: out[k][w] = sum_c M[k][c] * dw[c][w] ----
        {
            floatx4 dd[4];
            #pragma unroll
            for (int s = 0; s < 4; ++s) dd[s] = (floatx4){0.f, 0.f, 0.f, 0.f};

            #pragma unroll
            for (int sub = 0; sub < 4; ++sub) {
                const int cx = (q * 8) ^ (sub << 3);        // read-side un-swizzle
                const float* bp = &dwT[i & 1][sub * 16 + mrow][cx];
                fvec4 alo = *(const fvec4*)(bp);
                fvec4 ahi = *(const fvec4*)(bp + 4);
                fvec4 blo = *(const fvec4*)(bp + 32);
                fvec4 bhi = *(const fvec4*)(bp + 36);
                half8 hb0, hb1;
                #pragma unroll
                for (int j = 0; j < 4; ++j) {
                    hb0[j]     = (_Float16)alo[j];
                    hb0[j + 4] = (_Float16)ahi[j];
                    hb1[j]     = (_Float16)blo[j];
                    hb1[j + 4] = (_Float16)bhi[j];
                }
                dd[sub] = __builtin_amdgcn_mfma_f32_16x16x32_f16(af0, hb0, dd[sub], 0, 0, 0);
                dd[sub] = __builtin_amdgcn_mfma_f32_16x16x32_f16(af1, hb1, dd[sub], 0, 0, 0);
            }

            // D layout: col(w) = lane&15, row(k) = q*4 + reg
            float* obase = out + (((size_t)(b * CC + wave * 16 + q * 4)) * HH + (h0 + i)) * WW + tw0;
            #pragma unroll
            for (int r = 0; r < 4; ++r) {
                float* orow = obase + (size_t)r * kstride + mrow;
                #pragma unroll
                for (int sub = 0; sub < 4; ++sub)
                    __builtin_nontemporal_store(dd[sub][r], orow + sub * 16);
            }
        }
    }
}

extern "C" void kernel_launch(void* const* d_in, const int* in_sizes, int n_in,
                              void* d_out, int out_size, void* d_ws, size_t ws_size,
                              hipStream_t stream) {
    const float* x    = (const float*)d_in[0];  // [8,64,256,256]
    const float* dwgt = (const float*)d_in[1];  // [64,1,3,3]
    const float* pwgt = (const float*)d_in[2];  // [64,64,1,1]
    const float* attw = (const float*)d_in[3];  // [64,64]
    const float* gatt = (const float*)d_in[4];  // [64,64]
    _Float16* Mh = (_Float16*)d_ws;             // 4096 f16 = 8 KB
    float* o  = (float*)d_out;

    prep_M<<<1, 1024, 0, stream>>>(attw, gatt, pwgt, Mh);

    dim3 grid(WW / 64, HH / ROWS, NB);
    fused_conv_mix<<<grid, 256, 0, stream>>>(x, dwgt, Mh, o);
}